// Round 14
// baseline (152.212 us; speedup 1.0000x reference)
//
#include <hip/hip_runtime.h>
#include <hip/hip_bf16.h>
#include <cmath>

// Problem constants
#define S_LEN 2048
#define HIDN  1024
#define NHEAD 16
#define HDIM  64
#define NBAT  2

static constexpr long NA = (long)NBAT * S_LEN * HIDN;  // hidden elems
static constexpr long NW = (long)HIDN * HIDN;          // per weight
static constexpr long NM = (long)NBAT * S_LEN * S_LEN; // struct mask elems
static constexpr long NAM = (long)NBAT * S_LEN;        // amask elems

typedef __attribute__((ext_vector_type(8))) __bf16 bf16x8;
typedef __attribute__((ext_vector_type(4))) float f32x4;
typedef __attribute__((ext_vector_type(16))) float f32x16;

#define LOG2E 1.44269504088896340736f

__device__ __forceinline__ unsigned short f2bf(float f) {
  __hip_bfloat16 h = __float2bfloat16(f);
  unsigned short u;
  __builtin_memcpy(&u, &h, 2);
  return u;
}

// packed f32->bf16 RNE: low16 = bf16(a), high16 = bf16(b); 1 instr
__device__ __forceinline__ unsigned cvtpk(float a, float b) {
  unsigned r;
  asm volatile("v_cvt_pk_bf16_f32 %0, %1, %2" : "=v"(r) : "v"(a), "v"(b));
  return r;
}

__device__ __forceinline__ void gload_lds16(const void* g, void* l) {
  __builtin_amdgcn_global_load_lds(
      (const __attribute__((address_space(1))) void*)g,
      (__attribute__((address_space(3))) void*)l, 16, 0, 0);
}

// ---------------- kernel 1: fp32 -> bf16 conversions (+ amask prescale) ----------------
// Struct mask no longer converted: attn reads it fp32 directly.
__global__ __launch_bounds__(256) void convert_kernel(
    const float* __restrict__ hs, const float* __restrict__ wq,
    const float* __restrict__ wk, const float* __restrict__ wv,
    const float* __restrict__ amask, __hip_bfloat16* __restrict__ Abf,
    __hip_bfloat16* __restrict__ Wcat, float* __restrict__ amg) {
  const long tot4 = (NA + 3 * NW + NAM) >> 2;
  for (long i4 = (long)blockIdx.x * blockDim.x + threadIdx.x; i4 < tot4;
       i4 += (long)gridDim.x * blockDim.x) {
    long i = i4 << 2;
    if (i < NA + 3 * NW) {
      const float* s;
      __hip_bfloat16* dq;
      if (i < NA)               { s = hs + i;                 dq = Abf + i; }
      else if (i < NA + NW)     { s = wq + (i - NA);          dq = Wcat + (i - NA); }
      else if (i < NA + 2 * NW) { s = wk + (i - NA - NW);     dq = Wcat + (i - NA); }
      else                      { s = wv + (i - NA - 2 * NW); dq = Wcat + (i - NA); }
      float4 v = *(const float4*)s;
      union { unsigned short u[4]; uint2 p; } o;
      o.u[0] = f2bf(v.x); o.u[1] = f2bf(v.y); o.u[2] = f2bf(v.z); o.u[3] = f2bf(v.w);
      *(uint2*)dq = o.p;
    } else {
      long j = i - (NA + 3 * NW);
      float4 v = *(const float4*)(amask + j);
      v.x *= LOG2E; v.y *= LOG2E; v.z *= LOG2E; v.w *= LOG2E;
      *(float4*)(amg + j) = v;
    }
  }
}

// ---------------- kernel 2: QKV GEMM (m97 structure) ----------------
// q pre-scaled by c2 = log2(e)/sqrt(HD); V written TRANSPOSED [bh][d][s]
__global__ __launch_bounds__(256) void qkv_gemm(
    const __hip_bfloat16* __restrict__ A, const __hip_bfloat16* __restrict__ Bw,
    const float* __restrict__ bq, const float* __restrict__ bk,
    const float* __restrict__ bv, __hip_bfloat16* __restrict__ qb,
    __hip_bfloat16* __restrict__ kb, __hip_bfloat16* __restrict__ vtb) {
  __shared__ __hip_bfloat16 sA[128 * 32];
  __shared__ __hip_bfloat16 sB[128 * 32];

  int bid = blockIdx.x;
  int cpx = gridDim.x >> 3;
  int wg = (bid & 7) * cpx + (bid >> 3);
  int bm = wg / 24, bn = wg % 24;
  int tid = threadIdx.x, lane = tid & 63, wid = tid >> 6;
  int wr = wid >> 1, wc = wid & 1;
  int lr = lane & 15, hi = lane >> 4;
  int srow = lane >> 2, scol = (lane & 3) * 8;

  f32x4 acc[4][4] = {};

  for (int kt = 0; kt < 32; ++kt) {
    int k0 = kt * 32;
#pragma unroll
    for (int cc = 0; cc < 2; ++cc) {
      int c = wid * 2 + cc;
      const __hip_bfloat16* ga =
          A + ((size_t)(bm * 128 + c * 16 + srow) * 1024 + k0 + scol);
      gload_lds16(ga, (char*)sA + c * 1024);
      const __hip_bfloat16* gb =
          Bw + ((size_t)(bn * 128 + c * 16 + srow) * 1024 + k0 + scol);
      gload_lds16(gb, (char*)sB + c * 1024);
    }
    __syncthreads();
    bf16x8 af[4], bf[4];
#pragma unroll
    for (int mt = 0; mt < 4; ++mt)
      af[mt] = *(const bf16x8*)((const char*)sA +
                                ((wr * 64 + mt * 16 + lr) * 32 + hi * 8) * 2);
#pragma unroll
    for (int nt = 0; nt < 4; ++nt)
      bf[nt] = *(const bf16x8*)((const char*)sB +
                                ((wc * 64 + nt * 16 + lr) * 32 + hi * 8) * 2);
#pragma unroll
    for (int mt = 0; mt < 4; ++mt)
#pragma unroll
      for (int nt = 0; nt < 4; ++nt)
        acc[mt][nt] =
            __builtin_amdgcn_mfma_f32_16x16x32_bf16(af[mt], bf[nt], acc[mt][nt], 0, 0, 0);
    __syncthreads();
  }

  const float c2 = LOG2E / 8.0f;
#pragma unroll
  for (int nt = 0; nt < 4; ++nt) {
    int nb = bn * 128 + wc * 64 + nt * 16;
    int t = nb >> 10;
    int rem = nb & 1023;
    const float* bp = (t == 0) ? bq : (t == 1) ? bk : bv;
    float scl = (t == 0) ? c2 : 1.0f;
    int h = rem >> 6, d0r = rem & 63;
    float bias = bp[rem + lr];
    int d = d0r + lr;
#pragma unroll
    for (int mt = 0; mt < 4; ++mt) {
      int m0 = bm * 128 + wr * 64 + mt * 16 + hi * 4;
      int b = m0 >> 11, s = m0 & 2047;
      if (t == 2) {
        // V: transposed store [bh][d][s]; r=0..3 contiguous in s -> one 8B store
        union { unsigned short u[4]; uint2 p; } o;
#pragma unroll
        for (int r = 0; r < 4; ++r) o.u[r] = f2bf(acc[mt][nt][r] + bias);
        *(uint2*)(vtb + (((size_t)(b * NHEAD + h) * HDIM + d) * S_LEN + s)) = o.p;
      } else {
        __hip_bfloat16* ob = (t == 0) ? qb : kb;
#pragma unroll
        for (int r = 0; r < 4; ++r) {
          size_t off = (((size_t)(b * NHEAD + h)) * S_LEN + (s + r)) * HDIM + d;
          ob[off] = __float2bfloat16((acc[mt][nt][r] + bias) * scl);
        }
      }
    }
  }
}

// ---------------- kernel 3: KV-split flash attention, swapped-QK^T ----------------
// R13 structure (proven 87.7us) with ONE change: struct mask read directly as fp32
// (coalesced 4x16B loads + 8 permlane32_swap redistribution; no bf16 round-trip).
// 512 blocks x 512 threads (8 waves = 4 q-subtiles x 2 KV halves of 1024 keys).
// KVBLK=32 double-buffered; K [32][128B] + packed-V [32][128B] XOR-swizzled.
__global__ __launch_bounds__(512, 4) void attn_kernel(
    const __hip_bfloat16* __restrict__ qb, const __hip_bfloat16* __restrict__ kbuf,
    const __hip_bfloat16* __restrict__ vt, const float* __restrict__ Msk,
    const float* __restrict__ amg, const float* __restrict__ gate,
    float* __restrict__ out) {
  // [0,32768): KV [buf2][grp2][K 4KB | V 4KB]; [32768,40960): amask 2048 f32
  // merge aliases [0,34816) after the k-loop
  __shared__ alignas(16) char smem[40960];
  __shared__ float mlb[4][2][32];

  int bid = blockIdx.x;
  int wg = (bid & 7) * 64 + (bid >> 3);  // XCD swizzle (bijective, 512 = 8*64)
  int bi = wg >> 8, h = (wg >> 4) & 15, qt = wg & 15;
  int bh = bi * NHEAD + h;

  int tid = threadIdx.x;
  int lane = tid & 63, wid = tid >> 6;
  int grp = wid >> 2, w4 = wid & 3;
  int l31 = lane & 31, hi2 = lane >> 5;
  int qbase = qt * 128 + w4 * 32;
  int qrow = qbase + l31;
  int kbase = grp << 10;  // 1024-key half
  float g2 = gate[h] * LOG2E;

  const char* Kb = (const char*)kbuf + (size_t)bh * S_LEN * 128;
  const char* Vb = (const char*)vt + (size_t)bh * HDIM * S_LEN * 2;
  // fp32 mask row: lane owns q-row; hi2 selects the 8-key sub-block
  const char* Mrow =
      (const char*)Msk + (((size_t)bi * S_LEN + qrow) * S_LEN + hi2 * 8) * 4;

  // Q fragments (pre-scaled by log2e/8 in GEMM epilogue)
  bf16x8 qf[4];
  {
    const __hip_bfloat16* qp = qb + ((size_t)bh * S_LEN + qrow) * HDIM + hi2 * 8;
#pragma unroll
    for (int dc = 0; dc < 4; ++dc) qf[dc] = *(const bf16x8*)(qp + dc * 16);
  }

  int r8 = lane >> 3, ch = lane & 7, cs = ch ^ r8;  // staging swizzle (rule 21)
  int vD = w4 * 8 + r8 + ((cs >> 2) << 5);          // packed-V source d-row
  int vKoff = (cs & 3) << 4;

  auto stage = [&](int buf, int t) {
    int k0 = kbase + t * 32;
    char* base = smem + buf * 16384 + grp * 8192 + w4 * 1024;
    gload_lds16(Kb + (size_t)(k0 + w4 * 8 + r8) * 128 + (cs << 4), base);
    gload_lds16(Vb + (size_t)vD * 4096 + (size_t)k0 * 2 + vKoff, base + 4096);
  };

  // fp32 struct-mask prefetch: keys (pre-swap) hi2*8+[0..8) and 16+hi2*8+[0..8)
  float4 mf0, mf1, mf2, mf3;
  auto mload = [&](int t) {
    const char* p = Mrow + (size_t)(kbase + t * 32) * 4;
    mf0 = *(const float4*)(p);
    mf1 = *(const float4*)(p + 16);
    mf2 = *(const float4*)(p + 64);
    mf3 = *(const float4*)(p + 80);
  };

  const float* amq = (const float*)(smem + 32768) + grp * 1024;

  stage(0, 0);
  gload_lds16((const char*)amg + ((size_t)bi * S_LEN + wid * 256) * 4,
              smem + 32768 + wid * 1024);
  mload(0);
  __syncthreads();

  f32x16 O = {}, O2 = {};
  float m = -INFINITY, l = 0.f;

  for (int t = 0; t < 32; ++t) {
    int cur = t & 1;
    if (t < 31) stage(cur ^ 1, t + 1);

    // redistribute with (q,hi2)-partner: swap(a,b) = a.lanes[32:63] <-> b.lanes[0:31].
    // After swaps: mf0=rp0, mf1=rp1, mf2=rp2, mf3=rp3 (keys 8*rp+4*hi2+[0..4)).
    asm volatile("v_permlane32_swap_b32 %0, %1" : "+v"(mf0.x), "+v"(mf1.x));
    asm volatile("v_permlane32_swap_b32 %0, %1" : "+v"(mf0.y), "+v"(mf1.y));
    asm volatile("v_permlane32_swap_b32 %0, %1" : "+v"(mf0.z), "+v"(mf1.z));
    asm volatile("v_permlane32_swap_b32 %0, %1" : "+v"(mf0.w), "+v"(mf1.w));
    asm volatile("v_permlane32_swap_b32 %0, %1" : "+v"(mf2.x), "+v"(mf3.x));
    asm volatile("v_permlane32_swap_b32 %0, %1" : "+v"(mf2.y), "+v"(mf3.y));
    asm volatile("v_permlane32_swap_b32 %0, %1" : "+v"(mf2.z), "+v"(mf3.z));
    asm volatile("v_permlane32_swap_b32 %0, %1" : "+v"(mf2.w), "+v"(mf3.w));

    // C-init: st = g2*M + am  (k(reg) = (reg&3) + 8*(reg>>2) + 4*hi2)
    f32x16 st;
    {
      float4 amA = *(const float4*)(amq + t * 32 + 0 + hi2 * 4);
      float4 amB = *(const float4*)(amq + t * 32 + 8 + hi2 * 4);
      float4 amC = *(const float4*)(amq + t * 32 + 16 + hi2 * 4);
      float4 amD = *(const float4*)(amq + t * 32 + 24 + hi2 * 4);
      st[0]  = fmaf(mf0.x, g2, amA.x); st[1]  = fmaf(mf0.y, g2, amA.y);
      st[2]  = fmaf(mf0.z, g2, amA.z); st[3]  = fmaf(mf0.w, g2, amA.w);
      st[4]  = fmaf(mf1.x, g2, amB.x); st[5]  = fmaf(mf1.y, g2, amB.y);
      st[6]  = fmaf(mf1.z, g2, amB.z); st[7]  = fmaf(mf1.w, g2, amB.w);
      st[8]  = fmaf(mf2.x, g2, amC.x); st[9]  = fmaf(mf2.y, g2, amC.y);
      st[10] = fmaf(mf2.z, g2, amC.z); st[11] = fmaf(mf2.w, g2, amC.w);
      st[12] = fmaf(mf3.x, g2, amD.x); st[13] = fmaf(mf3.y, g2, amD.y);
      st[14] = fmaf(mf3.z, g2, amD.z); st[15] = fmaf(mf3.w, g2, amD.w);
    }
    if (t < 31) mload(t + 1);  // refill (consumed above)

    const char* sK = smem + cur * 16384 + grp * 8192;
    const char* sV = sK + 4096;

    // ---- S^T = K*Q^T + C ----
#pragma unroll
    for (int dc = 0; dc < 4; ++dc) {
      bf16x8 kf = *(const bf16x8*)(sK + l31 * 128 + (((dc * 2 + hi2) ^ (l31 & 7)) << 4));
      st = __builtin_amdgcn_mfma_f32_32x32x16_bf16(kf, qf[dc], st, 0, 0, 0);
    }

    // ---- online softmax (lane-local, q = l31) ----
    float pmax = -3.4e38f;
#pragma unroll
    for (int rp = 0; rp < 4; ++rp)
      pmax = fmaxf(pmax, fmaxf(fmaxf(st[rp * 4 + 0], st[rp * 4 + 1]),
                               fmaxf(st[rp * 4 + 2], st[rp * 4 + 3])));
    pmax = fmaxf(pmax, __shfl_xor(pmax, 32));
    if (__any(pmax > m + 8.f)) {  // defer-max (T13)
      float mnew = fmaxf(m, pmax);
      float alpha = exp2f(m - mnew);
      m = mnew;
      l *= alpha;
      O *= alpha;
      O2 *= alpha;
    }

    float rs0 = 0.f, rs1 = 0.f, rs2 = 0.f, rs3 = 0.f;
#pragma unroll
    for (int rp = 0; rp < 4; ++rp) {
      float p0 = exp2f(st[rp * 4 + 0] - m);
      float p1 = exp2f(st[rp * 4 + 1] - m);
      float p2 = exp2f(st[rp * 4 + 2] - m);
      float p3 = exp2f(st[rp * 4 + 3] - m);
      st[rp * 4 + 0] = p0; st[rp * 4 + 1] = p1;
      st[rp * 4 + 2] = p2; st[rp * 4 + 3] = p3;
      rs0 += p0; rs1 += p1; rs2 += p2; rs3 += p3;
    }
    float rs = (rs0 + rs1) + (rs2 + rs3);
    rs += __shfl_xor(rs, 32);
    l += rs;

    // ---- PV: O^T += V^T * P^T (cvt_pk + permlane32_swap pack) ----
#pragma unroll
    for (int ks = 0; ks < 2; ++ks) {
      unsigned A0 = cvtpk(st[ks * 8 + 0], st[ks * 8 + 1]);
      unsigned A1 = cvtpk(st[ks * 8 + 2], st[ks * 8 + 3]);
      unsigned B0 = cvtpk(st[ks * 8 + 4], st[ks * 8 + 5]);
      unsigned B1 = cvtpk(st[ks * 8 + 6], st[ks * 8 + 7]);
      asm volatile("v_permlane32_swap_b32 %0, %1" : "+v"(A0), "+v"(B0));
      asm volatile("v_permlane32_swap_b32 %0, %1" : "+v"(A1), "+v"(B1));
      union { unsigned w[4]; bf16x8 v; } Bf;
      Bf.w[0] = A0; Bf.w[1] = A1; Bf.w[2] = B0; Bf.w[3] = B1;
      bf16x8 v0 = *(const bf16x8*)(sV + l31 * 128 + (((ks * 2 + hi2) ^ (l31 & 7)) << 4));
      bf16x8 v1 = *(const bf16x8*)(sV + l31 * 128 + (((4 + ks * 2 + hi2) ^ (l31 & 7)) << 4));
      O = __builtin_amdgcn_mfma_f32_32x32x16_bf16(v0, Bf.v, O, 0, 0, 0);
      O2 = __builtin_amdgcn_mfma_f32_32x32x16_bf16(v1, Bf.v, O2, 0, 0, 0);
    }
    __syncthreads();  // readers done; drains next-tile stage
  }

  // ---- merge the two KV halves (group 1 -> LDS, group 0 combines + stores) ----
  float* mbuf = (float*)smem + w4 * (32 * 68);  // [q 32][d 68-padded] per wave-pair
  if (grp == 1) {
    if (hi2 == 0) { mlb[w4][0][l31] = m; mlb[w4][1][l31] = l; }
#pragma unroll
    for (int dt = 0; dt < 2; ++dt)
#pragma unroll
      for (int rq = 0; rq < 4; ++rq) {
        int d0 = dt * 32 + 8 * rq + 4 * hi2;
        const f32x16& Ox = dt ? O2 : O;
        f32x4 v = {Ox[rq * 4 + 0], Ox[rq * 4 + 1], Ox[rq * 4 + 2], Ox[rq * 4 + 3]};
        *(f32x4*)(mbuf + l31 * 68 + d0) = v;
      }
  }
  __syncthreads();
  if (grp == 0) {
    float m1 = mlb[w4][0][l31], l1 = mlb[w4][1][l31];
    float mx = fmaxf(m, m1);
    float a0 = exp2f(m - mx), a1 = exp2f(m1 - mx);
    float linv = 1.0f / (a0 * l + a1 * l1);
    a0 *= linv; a1 *= linv;
    float* orow = out + ((size_t)bi * S_LEN + qrow) * HIDN + h * HDIM;
#pragma unroll
    for (int dt = 0; dt < 2; ++dt)
#pragma unroll
      for (int rq = 0; rq < 4; ++rq) {
        int d0 = dt * 32 + 8 * rq + 4 * hi2;
        const f32x16& Ox = dt ? O2 : O;
        f32x4 v1 = *(const f32x4*)(mbuf + l31 * 68 + d0);
        float4 o;
        o.x = Ox[rq * 4 + 0] * a0 + v1[0] * a1;
        o.y = Ox[rq * 4 + 1] * a0 + v1[1] * a1;
        o.z = Ox[rq * 4 + 2] * a0 + v1[2] * a1;
        o.w = Ox[rq * 4 + 3] * a0 + v1[3] * a1;
        *(float4*)(orow + d0) = o;
      }
  }
}

extern "C" void kernel_launch(void* const* d_in, const int* in_sizes, int n_in,
                              void* d_out, int out_size, void* d_ws, size_t ws_size,
                              hipStream_t stream) {
  const float* hs    = (const float*)d_in[0];
  const float* amask = (const float*)d_in[1];
  const float* smask = (const float*)d_in[2];
  const float* Wq    = (const float*)d_in[3];
  const float* bq    = (const float*)d_in[4];
  const float* Wk    = (const float*)d_in[5];
  const float* bk    = (const float*)d_in[6];
  const float* Wv    = (const float*)d_in[7];
  const float* bv    = (const float*)d_in[8];
  const float* gate  = (const float*)d_in[9];

  char* ws = (char*)d_ws;
  __hip_bfloat16* Abf  = (__hip_bfloat16*)(ws);
  __hip_bfloat16* Wcat = (__hip_bfloat16*)(ws + 8388608);
  __hip_bfloat16* qb   = (__hip_bfloat16*)(ws + 8388608 + 6291456);
  __hip_bfloat16* kb   = qb + NA;
  __hip_bfloat16* vtr  = kb + NA;   // V stored transposed [bh][d][s]
  float*          amg  = (float*)(vtr + NA + NM);  // same ws offset as before

  convert_kernel<<<2048, 256, 0, stream>>>(hs, Wq, Wk, Wv, amask, Abf, Wcat, amg);
  qkv_gemm<<<768, 256, 0, stream>>>(Abf, Wcat, bq, bk, bv, qb, kb, vtr);
  attn_kernel<<<512, 512, 0, stream>>>(qb, kb, vtr, smask, amg, gate, (float*)d_out);
}

// Round 16
// 133.452 us; speedup vs baseline: 1.1406x; 1.1406x over previous
//
#include <hip/hip_runtime.h>
#include <hip/hip_bf16.h>
#include <cmath>

// Problem constants
#define S_LEN 2048
#define HIDN  1024
#define NHEAD 16
#define HDIM  64
#define NBAT  2

static constexpr long NA = (long)NBAT * S_LEN * HIDN;  // hidden elems
static constexpr long NW = (long)HIDN * HIDN;          // per weight
static constexpr long NM = (long)NBAT * S_LEN * S_LEN; // struct mask elems
static constexpr long NAM = (long)NBAT * S_LEN;        // amask elems

typedef __attribute__((ext_vector_type(8))) __bf16 bf16x8;
typedef __attribute__((ext_vector_type(4))) float f32x4;
typedef __attribute__((ext_vector_type(16))) float f32x16;

#define LOG2E 1.44269504088896340736f

__device__ __forceinline__ unsigned short f2bf(float f) {
  __hip_bfloat16 h = __float2bfloat16(f);
  unsigned short u;
  __builtin_memcpy(&u, &h, 2);
  return u;
}

__device__ __forceinline__ float bflo(unsigned u) {
  unsigned v = u << 16;
  float f;
  __builtin_memcpy(&f, &v, 4);
  return f;
}

__device__ __forceinline__ float bfhi(unsigned u) {
  unsigned v = u & 0xffff0000u;
  float f;
  __builtin_memcpy(&f, &v, 4);
  return f;
}

// packed f32->bf16 RNE: low16 = bf16(a), high16 = bf16(b); 1 instr
__device__ __forceinline__ unsigned cvtpk(float a, float b) {
  unsigned r;
  asm volatile("v_cvt_pk_bf16_f32 %0, %1, %2" : "=v"(r) : "v"(a), "v"(b));
  return r;
}

__device__ __forceinline__ void gload_lds16(const void* g, void* l) {
  __builtin_amdgcn_global_load_lds(
      (const __attribute__((address_space(1))) void*)g,
      (__attribute__((address_space(3))) void*)l, 16, 0, 0);
}

// ---------------- kernel 1: fp32 -> bf16 conversions (+ amask prescale) ----------------
__global__ __launch_bounds__(256) void convert_kernel(
    const float* __restrict__ hs, const float* __restrict__ wq,
    const float* __restrict__ wk, const float* __restrict__ wv,
    const float* __restrict__ mask, const float* __restrict__ amask,
    __hip_bfloat16* __restrict__ Abf, __hip_bfloat16* __restrict__ Wcat,
    __hip_bfloat16* __restrict__ Mbf, float* __restrict__ amg) {
  const long tot4 = (NA + 3 * NW + NM + NAM) >> 2;
  for (long i4 = (long)blockIdx.x * blockDim.x + threadIdx.x; i4 < tot4;
       i4 += (long)gridDim.x * blockDim.x) {
    long i = i4 << 2;
    if (i < NA + 3 * NW + NM) {
      const float* s;
      __hip_bfloat16* dq;
      if (i < NA)               { s = hs + i;                   dq = Abf + i; }
      else if (i < NA + NW)     { s = wq + (i - NA);            dq = Wcat + (i - NA); }
      else if (i < NA + 2 * NW) { s = wk + (i - NA - NW);       dq = Wcat + (i - NA); }
      else if (i < NA + 3 * NW) { s = wv + (i - NA - 2 * NW);   dq = Wcat + (i - NA); }
      else                      { s = mask + (i - NA - 3 * NW); dq = Mbf + (i - NA - 3 * NW); }
      float4 v = *(const float4*)s;
      union { unsigned short u[4]; uint2 p; } o;
      o.u[0] = f2bf(v.x); o.u[1] = f2bf(v.y); o.u[2] = f2bf(v.z); o.u[3] = f2bf(v.w);
      *(uint2*)dq = o.p;
    } else {
      long j = i - (NA + 3 * NW + NM);
      float4 v = *(const float4*)(amask + j);
      v.x *= LOG2E; v.y *= LOG2E; v.z *= LOG2E; v.w *= LOG2E;
      *(float4*)(amg + j) = v;
    }
  }
}

// ---------------- kernel 2: QKV GEMM (m97 structure) ----------------
// q pre-scaled by c2 = log2(e)/sqrt(HD); V written TRANSPOSED [bh][d][s]
__global__ __launch_bounds__(256) void qkv_gemm(
    const __hip_bfloat16* __restrict__ A, const __hip_bfloat16* __restrict__ Bw,
    const float* __restrict__ bq, const float* __restrict__ bk,
    const float* __restrict__ bv, __hip_bfloat16* __restrict__ qb,
    __hip_bfloat16* __restrict__ kb, __hip_bfloat16* __restrict__ vtb) {
  __shared__ __hip_bfloat16 sA[128 * 32];
  __shared__ __hip_bfloat16 sB[128 * 32];

  int bid = blockIdx.x;
  int cpx = gridDim.x >> 3;
  int wg = (bid & 7) * cpx + (bid >> 3);
  int bm = wg / 24, bn = wg % 24;
  int tid = threadIdx.x, lane = tid & 63, wid = tid >> 6;
  int wr = wid >> 1, wc = wid & 1;
  int lr = lane & 15, hi = lane >> 4;
  int srow = lane >> 2, scol = (lane & 3) * 8;

  f32x4 acc[4][4] = {};

  for (int kt = 0; kt < 32; ++kt) {
    int k0 = kt * 32;
#pragma unroll
    for (int cc = 0; cc < 2; ++cc) {
      int c = wid * 2 + cc;
      const __hip_bfloat16* ga =
          A + ((size_t)(bm * 128 + c * 16 + srow) * 1024 + k0 + scol);
      gload_lds16(ga, (char*)sA + c * 1024);
      const __hip_bfloat16* gb =
          Bw + ((size_t)(bn * 128 + c * 16 + srow) * 1024 + k0 + scol);
      gload_lds16(gb, (char*)sB + c * 1024);
    }
    __syncthreads();
    bf16x8 af[4], bf[4];
#pragma unroll
    for (int mt = 0; mt < 4; ++mt)
      af[mt] = *(const bf16x8*)((const char*)sA +
                                ((wr * 64 + mt * 16 + lr) * 32 + hi * 8) * 2);
#pragma unroll
    for (int nt = 0; nt < 4; ++nt)
      bf[nt] = *(const bf16x8*)((const char*)sB +
                                ((wc * 64 + nt * 16 + lr) * 32 + hi * 8) * 2);
#pragma unroll
    for (int mt = 0; mt < 4; ++mt)
#pragma unroll
      for (int nt = 0; nt < 4; ++nt)
        acc[mt][nt] =
            __builtin_amdgcn_mfma_f32_16x16x32_bf16(af[mt], bf[nt], acc[mt][nt], 0, 0, 0);
    __syncthreads();
  }

  const float c2 = LOG2E / 8.0f;
#pragma unroll
  for (int nt = 0; nt < 4; ++nt) {
    int nb = bn * 128 + wc * 64 + nt * 16;
    int t = nb >> 10;
    int rem = nb & 1023;
    const float* bp = (t == 0) ? bq : (t == 1) ? bk : bv;
    float scl = (t == 0) ? c2 : 1.0f;
    int h = rem >> 6, d0r = rem & 63;
    float bias = bp[rem + lr];
    int d = d0r + lr;
#pragma unroll
    for (int mt = 0; mt < 4; ++mt) {
      int m0 = bm * 128 + wr * 64 + mt * 16 + hi * 4;
      int b = m0 >> 11, s = m0 & 2047;
      if (t == 2) {
        // V: transposed store [bh][d][s]; r=0..3 contiguous in s -> one 8B store
        union { unsigned short u[4]; uint2 p; } o;
#pragma unroll
        for (int r = 0; r < 4; ++r) o.u[r] = f2bf(acc[mt][nt][r] + bias);
        *(uint2*)(vtb + (((size_t)(b * NHEAD + h) * HDIM + d) * S_LEN + s)) = o.p;
      } else {
        __hip_bfloat16* ob = (t == 0) ? qb : kb;
#pragma unroll
        for (int r = 0; r < 4; ++r) {
          size_t off = (((size_t)(b * NHEAD + h)) * S_LEN + (s + r)) * HDIM + d;
          ob[off] = __float2bfloat16((acc[mt][nt][r] + bias) * scl);
        }
      }
    }
  }
}

// ---------------- kernel 3: KV-split flash attention, swapped-QK^T ----------------
// R13 final (proven 87.7us attn, 133.7us total): 512 blocks x 512 threads
// (8 waves = 4 q-subtiles x 2 KV halves of 1024 keys). KVBLK=32 double-buffered;
// K [32][128B] + packed-V [32][128B] XOR-swizzled (conflict-free ds_read_b128).
// Struct mask: 2x16B coalesced bf16 loads + permlane32_swap redistribution,
// folded into the MFMA C-init. (512,4): proven no-spill envelope.
__global__ __launch_bounds__(512, 4) void attn_kernel(
    const __hip_bfloat16* __restrict__ qb, const __hip_bfloat16* __restrict__ kbuf,
    const __hip_bfloat16* __restrict__ vt, const __hip_bfloat16* __restrict__ Mbf,
    const float* __restrict__ amg, const float* __restrict__ gate,
    float* __restrict__ out) {
  // [0,32768): KV [buf2][grp2][K 4KB | V 4KB]; [32768,40960): amask 2048 f32
  // merge aliases [0,34816) after the k-loop
  __shared__ alignas(16) char smem[40960];
  __shared__ float mlb[4][2][32];

  int bid = blockIdx.x;
  int wg = (bid & 7) * 64 + (bid >> 3);  // XCD swizzle (bijective, 512 = 8*64)
  int bi = wg >> 8, h = (wg >> 4) & 15, qt = wg & 15;
  int bh = bi * NHEAD + h;

  int tid = threadIdx.x;
  int lane = tid & 63, wid = tid >> 6;
  int grp = wid >> 2, w4 = wid & 3;
  int l31 = lane & 31, hi2 = lane >> 5;
  int qbase = qt * 128 + w4 * 32;
  int qrow = qbase + l31;
  int kbase = grp << 10;  // 1024-key half
  float g2 = gate[h] * LOG2E;

  const char* Kb = (const char*)kbuf + (size_t)bh * S_LEN * 128;
  const char* Vb = (const char*)vt + (size_t)bh * HDIM * S_LEN * 2;
  const char* Mrow =
      (const char*)Mbf + ((size_t)bi * S_LEN + qrow) * S_LEN * 2 + hi2 * 16;

  // Q fragments (pre-scaled by log2e/8 in GEMM epilogue)
  bf16x8 qf[4];
  {
    const __hip_bfloat16* qp = qb + ((size_t)bh * S_LEN + qrow) * HDIM + hi2 * 8;
#pragma unroll
    for (int dc = 0; dc < 4; ++dc) qf[dc] = *(const bf16x8*)(qp + dc * 16);
  }

  int r8 = lane >> 3, ch = lane & 7, cs = ch ^ r8;  // staging swizzle (rule 21)
  int vD = w4 * 8 + r8 + ((cs >> 2) << 5);          // packed-V source d-row
  int vKoff = (cs & 3) << 4;

  auto stage = [&](int buf, int t) {
    int k0 = kbase + t * 32;
    char* base = smem + buf * 16384 + grp * 8192 + w4 * 1024;
    gload_lds16(Kb + (size_t)(k0 + w4 * 8 + r8) * 128 + (cs << 4), base);
    gload_lds16(Vb + (size_t)vD * 4096 + (size_t)k0 * 2 + vKoff, base + 4096);
  };

  unsigned ma0, ma1, ma2, ma3, mb0, mb1, mb2, mb3;
  auto mload = [&](int t) {
    const char* p = Mrow + (size_t)(kbase + t * 32) * 2;
    uint4 A = *(const uint4*)p;        // keys +hi2*8 .. +7
    uint4 B = *(const uint4*)(p + 32); // keys +16+hi2*8 ..
    ma0 = A.x; ma1 = A.y; ma2 = A.z; ma3 = A.w;
    mb0 = B.x; mb1 = B.y; mb2 = B.z; mb3 = B.w;
  };

  const float* amq = (const float*)(smem + 32768) + grp * 1024;

  stage(0, 0);
  gload_lds16((const char*)amg + ((size_t)bi * S_LEN + wid * 256) * 4,
              smem + 32768 + wid * 1024);
  mload(0);
  __syncthreads();

  f32x16 O = {}, O2 = {};
  float m = -INFINITY, l = 0.f;

  for (int t = 0; t < 32; ++t) {
    int cur = t & 1;
    if (t < 31) stage(cur ^ 1, t + 1);

    // redistribute mask regs with (q,hi2)-partner: after swaps, (ma0,ma1)=rp0,
    // (ma2,ma3)=rp1, (mb0,mb1)=rp2, (mb2,mb3)=rp3 on BOTH halves
    asm volatile("v_permlane32_swap_b32 %0, %1" : "+v"(ma0), "+v"(ma2));
    asm volatile("v_permlane32_swap_b32 %0, %1" : "+v"(ma1), "+v"(ma3));
    asm volatile("v_permlane32_swap_b32 %0, %1" : "+v"(mb0), "+v"(mb2));
    asm volatile("v_permlane32_swap_b32 %0, %1" : "+v"(mb1), "+v"(mb3));

    // C-init: st = g2*M + am  (k(reg) = (reg&3) + 8*(reg>>2) + 4*hi2)
    f32x16 st;
#pragma unroll
    for (int rp = 0; rp < 4; ++rp) {
      float4 am = *(const float4*)(amq + t * 32 + rp * 8 + hi2 * 4);
      unsigned d0 = (rp == 0) ? ma0 : (rp == 1) ? ma2 : (rp == 2) ? mb0 : mb2;
      unsigned d1 = (rp == 0) ? ma1 : (rp == 1) ? ma3 : (rp == 2) ? mb1 : mb3;
      st[rp * 4 + 0] = fmaf(bflo(d0), g2, am.x);
      st[rp * 4 + 1] = fmaf(bfhi(d0), g2, am.y);
      st[rp * 4 + 2] = fmaf(bflo(d1), g2, am.z);
      st[rp * 4 + 3] = fmaf(bfhi(d1), g2, am.w);
    }
    if (t < 31) mload(t + 1);  // refill for next tile (consumed above)

    const char* sK = smem + cur * 16384 + grp * 8192;
    const char* sV = sK + 4096;

    // ---- S^T = K*Q^T + C ----
#pragma unroll
    for (int dc = 0; dc < 4; ++dc) {
      bf16x8 kf = *(const bf16x8*)(sK + l31 * 128 + (((dc * 2 + hi2) ^ (l31 & 7)) << 4));
      st = __builtin_amdgcn_mfma_f32_32x32x16_bf16(kf, qf[dc], st, 0, 0, 0);
    }

    // ---- online softmax (lane-local, q = l31) ----
    float pmax = -3.4e38f;
#pragma unroll
    for (int rp = 0; rp < 4; ++rp)
      pmax = fmaxf(pmax, fmaxf(fmaxf(st[rp * 4 + 0], st[rp * 4 + 1]),
                               fmaxf(st[rp * 4 + 2], st[rp * 4 + 3])));
    pmax = fmaxf(pmax, __shfl_xor(pmax, 32));
    if (__any(pmax > m + 8.f)) {  // defer-max (T13)
      float mnew = fmaxf(m, pmax);
      float alpha = exp2f(m - mnew);
      m = mnew;
      l *= alpha;
      O *= alpha;
      O2 *= alpha;
    }

    float rs0 = 0.f, rs1 = 0.f, rs2 = 0.f, rs3 = 0.f;
#pragma unroll
    for (int rp = 0; rp < 4; ++rp) {
      float p0 = exp2f(st[rp * 4 + 0] - m);
      float p1 = exp2f(st[rp * 4 + 1] - m);
      float p2 = exp2f(st[rp * 4 + 2] - m);
      float p3 = exp2f(st[rp * 4 + 3] - m);
      st[rp * 4 + 0] = p0; st[rp * 4 + 1] = p1;
      st[rp * 4 + 2] = p2; st[rp * 4 + 3] = p3;
      rs0 += p0; rs1 += p1; rs2 += p2; rs3 += p3;
    }
    float rs = (rs0 + rs1) + (rs2 + rs3);
    rs += __shfl_xor(rs, 32);
    l += rs;

    // ---- PV: O^T += V^T * P^T (cvt_pk + permlane32_swap pack) ----
#pragma unroll
    for (int ks = 0; ks < 2; ++ks) {
      unsigned A0 = cvtpk(st[ks * 8 + 0], st[ks * 8 + 1]);
      unsigned A1 = cvtpk(st[ks * 8 + 2], st[ks * 8 + 3]);
      unsigned B0 = cvtpk(st[ks * 8 + 4], st[ks * 8 + 5]);
      unsigned B1 = cvtpk(st[ks * 8 + 6], st[ks * 8 + 7]);
      asm volatile("v_permlane32_swap_b32 %0, %1" : "+v"(A0), "+v"(B0));
      asm volatile("v_permlane32_swap_b32 %0, %1" : "+v"(A1), "+v"(B1));
      union { unsigned w[4]; bf16x8 v; } Bf;
      Bf.w[0] = A0; Bf.w[1] = A1; Bf.w[2] = B0; Bf.w[3] = B1;
      bf16x8 v0 = *(const bf16x8*)(sV + l31 * 128 + (((ks * 2 + hi2) ^ (l31 & 7)) << 4));
      bf16x8 v1 = *(const bf16x8*)(sV + l31 * 128 + (((4 + ks * 2 + hi2) ^ (l31 & 7)) << 4));
      O = __builtin_amdgcn_mfma_f32_32x32x16_bf16(v0, Bf.v, O, 0, 0, 0);
      O2 = __builtin_amdgcn_mfma_f32_32x32x16_bf16(v1, Bf.v, O2, 0, 0, 0);
    }
    __syncthreads();  // readers done; drains next-tile stage
  }

  // ---- merge the two KV halves (group 1 -> LDS, group 0 combines + stores) ----
  float* mbuf = (float*)smem + w4 * (32 * 68);  // [q 32][d 68-padded] per wave-pair
  if (grp == 1) {
    if (hi2 == 0) { mlb[w4][0][l31] = m; mlb[w4][1][l31] = l; }
#pragma unroll
    for (int dt = 0; dt < 2; ++dt)
#pragma unroll
      for (int rq = 0; rq < 4; ++rq) {
        int d0 = dt * 32 + 8 * rq + 4 * hi2;
        const f32x16& Ox = dt ? O2 : O;
        f32x4 v = {Ox[rq * 4 + 0], Ox[rq * 4 + 1], Ox[rq * 4 + 2], Ox[rq * 4 + 3]};
        *(f32x4*)(mbuf + l31 * 68 + d0) = v;
      }
  }
  __syncthreads();
  if (grp == 0) {
    float m1 = mlb[w4][0][l31], l1 = mlb[w4][1][l31];
    float mx = fmaxf(m, m1);
    float a0 = exp2f(m - mx), a1 = exp2f(m1 - mx);
    float linv = 1.0f / (a0 * l + a1 * l1);
    a0 *= linv; a1 *= linv;
    float* orow = out + ((size_t)bi * S_LEN + qrow) * HIDN + h * HDIM;
#pragma unroll
    for (int dt = 0; dt < 2; ++dt)
#pragma unroll
      for (int rq = 0; rq < 4; ++rq) {
        int d0 = dt * 32 + 8 * rq + 4 * hi2;
        const f32x16& Ox = dt ? O2 : O;
        f32x4 v1 = *(const f32x4*)(mbuf + l31 * 68 + d0);
        float4 o;
        o.x = Ox[rq * 4 + 0] * a0 + v1[0] * a1;
        o.y = Ox[rq * 4 + 1] * a0 + v1[1] * a1;
        o.z = Ox[rq * 4 + 2] * a0 + v1[2] * a1;
        o.w = Ox[rq * 4 + 3] * a0 + v1[3] * a1;
        *(float4*)(orow + d0) = o;
      }
  }
}

extern "C" void kernel_launch(void* const* d_in, const int* in_sizes, int n_in,
                              void* d_out, int out_size, void* d_ws, size_t ws_size,
                              hipStream_t stream) {
  const float* hs    = (const float*)d_in[0];
  const float* amask = (const float*)d_in[1];
  const float* smask = (const float*)d_in[2];
  const float* Wq    = (const float*)d_in[3];
  const float* bq    = (const float*)d_in[4];
  const float* Wk    = (const float*)d_in[5];
  const float* bk    = (const float*)d_in[6];
  const float* Wv    = (const float*)d_in[7];
  const float* bv    = (const float*)d_in[8];
  const float* gate  = (const float*)d_in[9];

  char* ws = (char*)d_ws;
  __hip_bfloat16* Abf  = (__hip_bfloat16*)(ws);
  __hip_bfloat16* Wcat = (__hip_bfloat16*)(ws + 8388608);
  __hip_bfloat16* qb   = (__hip_bfloat16*)(ws + 8388608 + 6291456);
  __hip_bfloat16* kb   = qb + NA;
  __hip_bfloat16* vtr  = kb + NA;   // V stored transposed [bh][d][s]
  __hip_bfloat16* Mbf  = vtr + NA;
  float*          amg  = (float*)(Mbf + NM);

  convert_kernel<<<2048, 256, 0, stream>>>(hs, Wq, Wk, Wv, smask, amask, Abf, Wcat, Mbf, amg);
  qkv_gemm<<<768, 256, 0, stream>>>(Abf, Wcat, bq, bk, bv, qb, kb, vtr);
  attn_kernel<<<512, 512, 0, stream>>>(qb, kb, vtr, Mbf, amg, gate, (float*)d_out);
}